// Round 15
// baseline (276.560 us; speedup 1.0000x reference)
//
#include <hip/hip_runtime.h>
#include <hip/hip_bf16.h>

#define Bq   8
#define Tq   16
#define Nq   1024
#define Cq   48
#define Gq   32
#define Hq   150
#define H3q  450
#define TAq  32
#define OUTq 1024
#define BTq  128

#define NC_CAP 128   // active code / neighbor rows per (b,t): Binom(1024,.06) mean 61 sd 7.6
#define NM_CAP 64    // m1 / m23 rows per (b,t): Binom(1024,.03) mean 30.7 sd 5.5
#define NACT   (2 * NC_CAP)
#define MTILE  16
#define NMQ    (NM_CAP / 4)

__device__ __forceinline__ float lrelu(float x){ return x > 0.f ? x : 0.01f * x; }
__device__ __forceinline__ float sigm(float x){ return 1.f / (1.f + expf(-x)); }

// -------- device-global scratch (everything read is written earlier in the same call) --------
__device__ int   g_n1[BTq], g_n23[BTq], g_nchain[BTq], g_nchain2[BTq];
__device__ short g_list1[BTq][NM_CAP];
__device__ short g_list23[BTq][NM_CAP];        // row | (m2 ? 0x400 : 0), ascending row order
__device__ short g_mapc[BTq][Nq];              // row -> slot in c-list (-1 if inactive)
__device__ short g_mapn[BTq][Nq];              // row -> slot in nb-list (-1 if inactive)
__device__ int   g_chain[BTq][NM_CAP];         // (i_slot << 16) | prev_slot for m1->m1 rows
__device__ int   g_chain2[BTq][NM_CAP];        // deep-chain subset (source itself chain at t-1)
__device__ unsigned char g_cls[BTq][NM_CAP];   // per-m1-row class: 0 plain, 1 chain, 2 m23-sourced
__device__ float g_co[BTq][NC_CAP][Gq];        // co at active c rows (slot order)
__device__ float g_no[BTq][NC_CAP][Gq];        // no at active nb rows (slot order)
__device__ float g_hm23[BTq][NM_CAP][Hq];      // tanh(P@v) — ONLY rows m1 at t+1 are written/read
__device__ float g_om23p4[4][BTq][Hq];         // om23 partial max per query-quarter
__device__ float g_hm1[BTq][NM_CAP][Hq];       // GRU outputs at m1 rows (slot = list1 index)
__device__ float g_om1p4[4][BTq][Hq];          // om1 partial max over NON-chain m1 rows, per quarter
__device__ float g_om1c[BTq][Hq];              // om1 max over depth-1 chain rows (k_gru1b)

// inline gi helper (rare chain rows only, ~1/block): gi = bi + co @ Wi at column h
__device__ __forceinline__ void gi3(const float* co_row, const float* Wi, const float* bi, int h,
                                    float& gr, float& gz, float& gn){
    gr = bi[h]; gz = bi[Hq + h]; gn = bi[2 * Hq + h];
    #pragma unroll
    for (int g = 0; g < Gq; ++g){
        float c = co_row[g];
        const float* w = Wi + g * H3q + h;
        gr += c * w[0];
        gz += c * w[Hq];
        gn += c * w[2 * Hq];
    }
}

// -------- K_co (4 blocks per (b,t), m-row quarters): lists, maps, Pact (=emb@Wg, k_pre folded),
// then tiled gathered-GEMM for co/no --------
__global__ __launch_bounds__(512) void k_co(const float* code_x, const float* neighbors,
                                            const float* adj, const float* Wg, const float* bg,
                                            const float* c_emb, const float* n_emb){
    int bt = blockIdx.x >> 2, quarter = blockIdx.x & 3, tid = threadIdx.x;
    __shared__ unsigned char cf_s[Nq], nf_s[Nq];   // 2 KB staged activity flags
    __shared__ float Wg_s[Cq][Gq];                 // 6 KB
    __shared__ short lc_s[NC_CAP], ln_s[NC_CAP];
    __shared__ short act_s[NACT];
    __shared__ int nc_s, nn_s;
    __shared__ float Pact_s[NACT][Gq];             // 32 KB
    __shared__ float A_s[MTILE][NACT];             // 16 KB
    __shared__ short mrow_s[MTILE];
    int wave = tid >> 6, lane = tid & 63;

    for (int n = tid; n < Nq; n += 512){
        cf_s[n] = (code_x[bt * Nq + n]    > 0.f) ? 1 : 0;
        nf_s[n] = (neighbors[bt * Nq + n] > 0.f) ? 1 : 0;
    }
    for (int idx = tid; idx < Cq * Gq; idx += 512) (&Wg_s[0][0])[idx] = Wg[idx];
    if (quarter == 0) for (int n = tid; n < Nq; n += 512) g_mapc[bt][n] = -1;
    if (quarter == 1) for (int n = tid; n < Nq; n += 512) g_mapn[bt][n] = -1;
    __syncthreads();
    if (wave == 0){           // compact c-active rows (ballot over LDS flags)
        int base = 0;
        for (int start = 0; start < Nq; start += 64){
            int n = start + lane;
            int pred = cf_s[n];
            unsigned long long mm = __ballot(pred != 0);
            int pos = base + (int)__popcll(mm & ((1ull << lane) - 1ull));
            if (pred && pos < NC_CAP) lc_s[pos] = (short)n;
            base += (int)__popcll(mm);
        }
        if (lane == 0) nc_s = min(base, NC_CAP);
    } else if (wave == 1){    // compact nb-active rows
        int base = 0;
        for (int start = 0; start < Nq; start += 64){
            int n = start + lane;
            int pred = nf_s[n];
            unsigned long long mm = __ballot(pred != 0);
            int pos = base + (int)__popcll(mm & ((1ull << lane) - 1ull));
            if (pred && pos < NC_CAP) ln_s[pos] = (short)n;
            base += (int)__popcll(mm);
        }
        if (lane == 0) nn_s = min(base, NC_CAP);
    }
    __syncthreads();
    int nc = nc_s, nn = nn_s, total = nc + nn;
    for (int i = tid; i < total; i += 512) act_s[i] = (i < nc) ? lc_s[i] : ln_s[i - nc];
    __syncthreads();
    if (quarter == 0) for (int i = tid; i < nc; i += 512) g_mapc[bt][lc_s[i]] = (short)i;
    if (quarter == 1) for (int i = tid; i < nn; i += 512) g_mapn[bt][ln_s[i]] = (short)i;
    // Pact = emb @ Wg computed in-block (k_pre folded; emb row reads are lane-broadcast, L2-hot)
    for (int idx = tid; idx < total * Gq; idx += 512){
        int i = idx >> 5, g = idx & 31;
        int row = act_s[i];
        const float* emb = (i < nc) ? (c_emb + (size_t)row * Cq) : (n_emb + (size_t)row * Cq);
        float acc = 0.f;
        #pragma unroll
        for (int c = 0; c < Cq; ++c) acc += emb[c] * Wg_s[c][g];
        Pact_s[i][g] = acc;
    }
    __syncthreads();

    int g = tid & 31, grp = tid >> 5;
    float bgv = bg[g];
    for (int rbase = quarter; rbase < total; rbase += 4 * MTILE){
        if (tid < MTILE){
            int r = rbase + 4 * tid;
            mrow_s[tid] = (r < total) ? act_s[r] : 0;
        }
        __syncthreads();
        int ntile = min(MTILE, (total - rbase + 3) >> 2);
        for (int idx = tid; idx < ntile * total; idx += 512){
            int ti = idx / total, j = idx % total;
            A_s[ti][j] = adj[(size_t)mrow_s[ti] * Nq + act_s[j]];
        }
        __syncthreads();
        if (grp < ntile){
            int r = rbase + 4 * grp;
            float agg = 0.f;
            #pragma unroll 4
            for (int j = 0; j < total; ++j) agg += A_s[grp][j] * Pact_s[j][g];
            float v = lrelu(Pact_s[r][g] + agg + bgv);
            if (r < nc) g_co[bt][r][g]      = v;
            else        g_no[bt][r - nc][g] = v;
        }
        __syncthreads();
    }
}

// -------- K_mid (4 blocks per (b,t), query quarters): lists + attention in LDS --------
__global__ __launch_bounds__(512) void k_mid(const float* divided, const float* u_emb,
                                             const float* Wk, const float* bk,
                                             const float* Wq_, const float* bq_,
                                             const float* Wv_, const float* bv_,
                                             const float* bg){
    int bt = blockIdx.x >> 2, quarter = blockIdx.x & 3, tid = threadIdx.x;
    int t = bt % Tq, btp = bt - 1;
    __shared__ unsigned char f1_s[Nq], f2_s[Nq], f3_s[Nq];   // 3 KB staged divided flags
    __shared__ short l1_s[NM_CAP], l23_s[NM_CAP];
    __shared__ unsigned char wm_s[NMQ];
    __shared__ int n1_s, n23_s;
    __shared__ float qr_s[NM_CAP][Gq];           // 8 KB (all rows; v needs all)
    __shared__ float q_s[NMQ][TAq + 1];          // my queries
    __shared__ float k_s[NM_CAP][TAq + 1];       // all keys
    __shared__ float s_s[NMQ][NM_CAP + 1];       // my scores
    __shared__ float vv_s[NM_CAP][Hq];           // 38.4 KB (all values)
    __shared__ float hm_s[NMQ][Hq];              // 9.6 KB (my outputs)
    int wave = tid >> 6, lane = tid & 63;

    for (int idx = tid; idx < Nq * 3; idx += 512){
        float v = divided[(size_t)bt * Nq * 3 + idx];
        int n = idx / 3, c = idx - n * 3;
        unsigned char f = (v > 0.f) ? 1 : 0;
        if (c == 0) f1_s[n] = f;
        else if (c == 1) f2_s[n] = f;
        else f3_s[n] = f;
    }
    __syncthreads();
    if (wave == 0){           // m1 list (ballot over LDS flags)
        int base = 0;
        for (int start = 0; start < Nq; start += 64){
            int n = start + lane;
            int pred = f1_s[n];
            unsigned long long mm = __ballot(pred != 0);
            int pos = base + (int)__popcll(mm & ((1ull << lane) - 1ull));
            if (pred && pos < NM_CAP) l1_s[pos] = (short)n;
            base += (int)__popcll(mm);
        }
        if (lane == 0) n1_s = min(base, NM_CAP);
    } else if (wave == 1){    // m23 list with m2 tag
        int base = 0;
        for (int start = 0; start < Nq; start += 64){
            int n = start + lane;
            int m2 = f2_s[n], m3 = f3_s[n];
            int pred = m2 | m3;
            unsigned long long mm = __ballot(pred != 0);
            int pos = base + (int)__popcll(mm & ((1ull << lane) - 1ull));
            if (pred && pos < NM_CAP) l23_s[pos] = (short)(n | (m2 ? 0x400 : 0));
            base += (int)__popcll(mm);
        }
        if (lane == 0) n23_s = min(base, NM_CAP);
    }
    __syncthreads();
    int n1 = n1_s, n23 = n23_s;
    if (quarter == 0){
        for (int i = tid; i < n1;  i += 512) g_list1[bt][i]  = l1_s[i];
        for (int i = tid; i < n23; i += 512) g_list23[bt][i] = l23_s[i];
        if (tid == 0){ g_n1[bt] = n1; g_n23[bt] = n23; }
    }
    if (t == 0 || n23 == 0) return;   // block-uniform; attention applies only at t>=1
    int nMy = (n23 > quarter) ? ((n23 - quarter + 3) >> 2) : 0;   // queries i with (i&3)==quarter

    // hm23 row is read downstream ONLY if its row is m1 at t+1 (k_gru1's m23-sourced GRU)
    for (int il = tid; il < nMy; il += 512){
        int row = l23_s[4 * il + quarter] & 1023;
        unsigned char wm = 0;
        if (t < Tq - 1) wm = (divided[((size_t)(bt + 1) * Nq + row) * 3] > 0.f) ? 1 : 0;
        wm_s[il] = wm;
    }
    for (int idx = tid; idx < n23 * Gq; idx += 512){
        int i = idx >> 5, g = idx & 31;
        int e = l23_s[i], row = e & 1023;
        float qv;
        if (e & 0x400){
            int slot = g_mapn[btp][row];
            qv = (slot >= 0) ? g_no[btp][slot][g] : lrelu(bg[g]);
        } else {
            qv = u_emb[row * Gq + g];
        }
        qr_s[i][g] = qv;
    }
    __syncthreads();
    // k for ALL keys (co read from L2, lane-broadcast); q for MY queries; v for ALL rows
    for (int idx = tid; idx < n23 * TAq; idx += 512){
        int i = idx >> 5, a = idx & 31;
        const float* corow = g_co[bt][g_mapc[bt][l23_s[i] & 1023]];
        float acck = bk[a];
        #pragma unroll
        for (int g = 0; g < Gq; ++g) acck += corow[g] * Wk[g * TAq + a];
        k_s[i][a] = acck;
    }
    for (int idx = tid; idx < nMy * TAq; idx += 512){
        int il = idx >> 5, a = idx & 31;
        int i = 4 * il + quarter;
        float accq = bq_[a];
        #pragma unroll
        for (int g = 0; g < Gq; ++g) accq += qr_s[i][g] * Wq_[g * TAq + a];
        q_s[il][a] = accq;
    }
    for (int idx = tid; idx < n23 * Hq; idx += 512){
        int i = idx / Hq, h = idx % Hq;
        float acc = bv_[h];
        #pragma unroll
        for (int g = 0; g < Gq; ++g) acc += qr_s[i][g] * Wv_[g * Hq + h];
        vv_s[i][h] = acc;
    }
    __syncthreads();

    const float scale = 0.17677669529663687f;   // 1/sqrt(32)
    for (int idx = tid; idx < nMy * n23; idx += 512){
        int il = idx / n23, j = idx % n23;
        float acc = 0.f;
        #pragma unroll
        for (int a = 0; a < TAq; ++a) acc += q_s[il][a] * k_s[j][a];
        s_s[il][j] = acc * scale;
    }
    __syncthreads();
    for (int il = tid; il < nMy; il += 512){     // per-query softmax over the m23 key set
        float mx = -1e30f;
        for (int j = 0; j < n23; ++j) mx = fmaxf(mx, s_s[il][j]);
        float sum = 0.f;
        for (int j = 0; j < n23; ++j){ float e = expf(s_s[il][j] - mx); s_s[il][j] = e; sum += e; }
        float inv = 1.f / sum;
        for (int j = 0; j < n23; ++j) s_s[il][j] *= inv;
    }
    __syncthreads();
    for (int idx = tid; idx < nMy * Hq; idx += 512){
        int il = idx / Hq, h = idx % Hq;
        float acc = 0.f;
        for (int j = 0; j < n23; ++j) acc += s_s[il][j] * vv_s[j][h];
        hm_s[il][h] = tanhf(acc);
    }
    __syncthreads();
    for (int idx = tid; idx < nMy * Hq; idx += 512){   // spill only rows k_gru1 will read
        int il = idx / Hq, h = idx % Hq;
        if (wm_s[il]) g_hm23[bt][4 * il + quarter][h] = hm_s[il][h];
    }
    for (int h = tid; h < Hq; h += 512){
        float mx = -1e30f;
        for (int il = 0; il < nMy; ++il) mx = fmaxf(mx, hm_s[il][h]);
        g_om23p4[quarter][bt][h] = mx;
    }
}

// -------- K_gru1 (4 blocks per (b,t), m1-row quarters): coop gi in LDS, GRU in place --------
__global__ __launch_bounds__(512) void k_gru1(const float* Wi, const float* bi,
                                              const float* Wh, const float* bh){
    int bt = blockIdx.x >> 2, quarter = blockIdx.x & 3, tid = threadIdx.x;
    int t = bt % Tq, btp = bt - 1;
    __shared__ short map1p[Nq], map23p[Nq];      // 4 KB
    __shared__ short l1_s[NM_CAP];
    __shared__ unsigned char cls_s[NM_CAP];      // 0=plain, 1=chain, 2=m23-sourced (all rows)
    __shared__ int m23l_s[NM_CAP];               // my quarter's (i<<16)|prev_slot
    __shared__ int nf23_s;
    __shared__ float co1_s[NMQ][Gq];             // 2 KB (my rows, local index il = i>>2)
    __shared__ float hb_s[Hq];
    __shared__ float ghf_s[H3q];
    __shared__ float gi_s[NMQ][H3q];             // 28.8 KB; cols [0,Hq) overwritten with hm1
    int n1 = g_n1[bt];
    int nMy = (n1 > quarter) ? ((n1 - quarter + 3) >> 2) : 0;   // rows i with (i&3)==quarter
    for (int n = tid; n < Nq; n += 512){ map1p[n] = -1; map23p[n] = -1; }
    for (int i = tid; i < n1; i += 512) l1_s[i] = g_list1[bt][i];
    __syncthreads();
    if (t >= 1){
        int n1p = g_n1[btp];
        for (int i = tid; i < n1p; i += 512) map1p[g_list1[btp][i]] = (short)i;
        if (t >= 2){
            int n23p = g_n23[btp];
            for (int i = tid; i < n23p; i += 512) map23p[g_list23[btp][i] & 1023] = (short)i;
        }
    }
    __syncthreads();
    if (tid < 64){                                // single wave: classify + ballot-compact
        int i = tid;
        int cls = 0, sp = -1;
        if (i < n1 && t >= 1){
            int row = l1_s[i];
            if (map1p[row] >= 0){ cls = 1; sp = map1p[row]; }
            else if (t >= 2 && map23p[row] >= 0){ cls = 2; sp = map23p[row]; }
        }
        if (i < n1) cls_s[i] = (unsigned char)cls;
        if (quarter == 0 && i < n1) g_cls[bt][i] = (unsigned char)cls;
        unsigned long long mch = __ballot(cls == 1);
        unsigned long long m23 = __ballot(cls == 2 && (i & 3) == quarter);
        int pch = (int)__popcll(mch & ((1ull << i) - 1ull));
        int p23 = (int)__popcll(m23 & ((1ull << i) - 1ull));
        if (quarter == 0 && cls == 1) g_chain[bt][pch] = (i << 16) | sp;
        if (cls == 2 && (i & 3) == quarter) m23l_s[p23] = (i << 16) | sp;
        if (i == 0){
            nf23_s = (int)__popcll(m23);
            if (quarter == 0) g_nchain[bt] = (int)__popcll(mch);
        }
    }
    // stage co rows for MY m1 rows
    for (int idx = tid; idx < nMy * Gq; idx += 512){
        int il = idx >> 5, g = idx & 31;
        co1_s[il][g] = g_co[bt][g_mapc[bt][l1_s[4 * il + quarter]]][g];
    }
    __syncthreads();

    // cooperative gi: thread j < 450 holds Wi column in regs (Wi read once per block, coalesced)
    if (tid < H3q){
        float wcol[Gq];
        #pragma unroll
        for (int g = 0; g < Gq; ++g) wcol[g] = Wi[g * H3q + tid];
        float bij = bi[tid];
        for (int il = 0; il < nMy; ++il){
            float acc = bij;
            #pragma unroll
            for (int g = 0; g < Gq; ++g) acc += co1_s[il][g] * wcol[g];
            gi_s[il][tid] = acc;
        }
    }
    __syncthreads();

    // plain rows (mine): hp = 0, gh = bias only. Thread (il,h) sole reader+writer of gi_s[il][h]
    for (int idx = tid; idx < nMy * Hq; idx += 512){
        int il = idx / Hq, h = idx % Hq;
        int i = 4 * il + quarter;
        if (cls_s[i] != 0) continue;
        float gr = gi_s[il][h], gz = gi_s[il][Hq + h], gn = gi_s[il][2 * Hq + h];
        float r  = sigm(gr + bh[h]);
        float z  = sigm(gz + bh[Hq + h]);
        float ng = tanhf(gn + r * bh[2 * Hq + h]);
        gi_s[il][h] = (1.f - z) * ng;
    }
    __syncthreads();

    // m23-sourced rows in my quarter (~0.25 per block): full Wh matvec + GRU
    int nf23 = nf23_s;
    for (int f = 0; f < nf23; ++f){
        int pk = m23l_s[f]; int i = pk >> 16, sp = pk & 0xffff;
        int il = i >> 2;
        for (int h = tid; h < Hq; h += 512) hb_s[h] = g_hm23[btp][sp][h];
        __syncthreads();
        for (int j = tid; j < H3q; j += 512){
            float acc = bh[j];
            for (int k2 = 0; k2 < Hq; ++k2) acc += hb_s[k2] * Wh[k2 * H3q + j];
            ghf_s[j] = acc;
        }
        __syncthreads();
        for (int h = tid; h < Hq; h += 512){
            float gr = gi_s[il][h], gz = gi_s[il][Hq + h], gn = gi_s[il][2 * Hq + h];
            float r  = sigm(gr + ghf_s[h]);
            float z  = sigm(gz + ghf_s[Hq + h]);
            float ng = tanhf(gn + r * ghf_s[2 * Hq + h]);
            gi_s[il][h] = (1.f - z) * ng + z * hb_s[h];
        }
        __syncthreads();
    }

    // write my non-chain hm1 + my om1 partial max (chain rows: k_gru1b / k_gru2f)
    for (int idx = tid; idx < nMy * Hq; idx += 512){
        int il = idx / Hq, h = idx % Hq;
        int i = 4 * il + quarter;
        if (cls_s[i] != 1) g_hm1[bt][i][h] = gi_s[il][h];
    }
    for (int h = tid; h < Hq; h += 512){
        float mx = -1e30f;
        for (int il = 0; il < nMy; ++il)
            if (cls_s[4 * il + quarter] != 1) mx = fmaxf(mx, gi_s[il][h]);
        g_om1p4[quarter][bt][h] = mx;
    }
}

// -------- K_gru1b (parallel): depth-1 chain rows; defers deep-chain rows into g_chain2 --------
__global__ __launch_bounds__(512) void k_gru1b(const float* Wi, const float* bi,
                                               const float* Wh, const float* bh){
    int bt = blockIdx.x, tid = threadIdx.x;
    int t = bt % Tq, btp = bt - 1;
    __shared__ unsigned char defer_s[NM_CAP];
    __shared__ float co_s[Gq];
    __shared__ float hb_s[Hq];
    __shared__ float ghf_s[H3q];
    __shared__ float cmax_s[Hq];
    int nch = (t > 0) ? g_nchain[bt] : 0;
    for (int h = tid; h < Hq; h += 512) cmax_s[h] = -1e30f;
    if (tid < 64){
        int c = tid;
        int defer = 0;
        if (c < nch){
            int sp = g_chain[bt][c] & 0xffff;
            defer = (g_cls[btp][sp] == 1) ? 1 : 0;   // source is chain at t-1 -> defer
            defer_s[c] = (unsigned char)defer;
        }
        unsigned long long md = __ballot((c < nch) && defer);
        int pos = (int)__popcll(md & ((1ull << c) - 1ull));
        if ((c < nch) && defer) g_chain2[bt][pos] = g_chain[bt][c];
        if (c == 0) g_nchain2[bt] = (int)__popcll(md);
    }
    __syncthreads();
    for (int c = 0; c < nch; ++c){
        if (defer_s[c]) continue;                    // block-uniform
        int pk = g_chain[bt][c]; int i = pk >> 16, sp = pk & 0xffff;
        if (tid < Gq) co_s[tid] = g_co[bt][g_mapc[bt][g_list1[bt][i]]][tid];
        for (int h = tid; h < Hq; h += 512) hb_s[h] = g_hm1[btp][sp][h];
        __syncthreads();
        for (int j = tid; j < H3q; j += 512){
            float acc = bh[j];
            for (int k2 = 0; k2 < Hq; ++k2) acc += hb_s[k2] * Wh[k2 * H3q + j];
            ghf_s[j] = acc;
        }
        __syncthreads();
        for (int h = tid; h < Hq; h += 512){
            float gr, gz, gn;
            gi3(co_s, Wi, bi, h, gr, gz, gn);
            float r  = sigm(gr + ghf_s[h]);
            float z  = sigm(gz + ghf_s[Hq + h]);
            float ng = tanhf(gn + r * ghf_s[2 * Hq + h]);
            float v  = (1.f - z) * ng + z * hb_s[h];
            g_hm1[bt][i][h] = v;
            cmax_s[h] = fmaxf(cmax_s[h], v);
        }
        __syncthreads();
    }
    for (int h = tid; h < Hq; h += 512) g_om1c[bt][h] = cmax_s[h];
}

// -------- K_gru2f (8 blocks): serial deep-chain rows (~3 total), then outs + attention + classifier
__global__ __launch_bounds__(512) void k_gru2f(const float* Wi, const float* bi,
                                               const float* Wh, const float* bh,
                                               const int* lens, const float* Wd, const float* bd,
                                               const float* ctx, const float* Wc, const float* bc,
                                               float* out){
    int b = blockIdx.x, tid = threadIdx.x;
    __shared__ float co_s[Gq];
    __shared__ float hb_s[Hq];
    __shared__ float ghf_s[H3q];
    __shared__ float outs_s[Tq][Hq];
    __shared__ float wdc_s[Hq];
    __shared__ float score_s[Tq];
    __shared__ float pooled_s[Hq];
    for (int t = 1; t < Tq; ++t){
        int bt = b * Tq + t, btp = bt - 1;
        int nch2 = g_nchain2[bt];
        for (int c = 0; c < nch2; ++c){
            int pk = g_chain2[bt][c]; int i = pk >> 16, sp = pk & 0xffff;
            if (tid < Gq) co_s[tid] = g_co[bt][g_mapc[bt][g_list1[bt][i]]][tid];
            for (int h = tid; h < Hq; h += 512) hb_s[h] = g_hm1[btp][sp][h];
            __syncthreads();
            for (int j = tid; j < H3q; j += 512){
                float acc = bh[j];
                for (int k2 = 0; k2 < Hq; ++k2) acc += hb_s[k2] * Wh[k2 * H3q + j];
                ghf_s[j] = acc;
            }
            __syncthreads();
            for (int h = tid; h < Hq; h += 512){
                float gr, gz, gn;
                gi3(co_s, Wi, bi, h, gr, gz, gn);
                float r  = sigm(gr + ghf_s[h]);
                float z  = sigm(gz + ghf_s[Hq + h]);
                float ng = tanhf(gn + r * ghf_s[2 * Hq + h]);
                g_hm1[bt][i][h] = (1.f - z) * ng + z * hb_s[h];
            }
            __syncthreads();
        }
    }
    // ---- finalize outs + temporal attention + classifier ----
    for (int idx = tid; idx < Tq * Hq; idx += 512){
        int t = idx / Hq, h = idx % Hq;
        int bt = b * Tq + t;
        int n1 = g_n1[bt], n23 = (t > 0) ? g_n23[bt] : 0;
        float o = 0.f;
        if (n1 > 0){
            float mx = fmaxf(fmaxf(g_om1p4[0][bt][h], g_om1p4[1][bt][h]),
                             fmaxf(g_om1p4[2][bt][h], g_om1p4[3][bt][h]));
            mx = fmaxf(mx, g_om1c[bt][h]);
            int nd = (t > 0) ? g_nchain2[bt] : 0;
            for (int c = 0; c < nd; ++c){
                int i = g_chain2[bt][c] >> 16;
                mx = fmaxf(mx, g_hm1[bt][i][h]);
            }
            o = mx;
        }
        if (n23 > 0){
            float m23x = fmaxf(fmaxf(g_om23p4[0][bt][h], g_om23p4[1][bt][h]),
                               fmaxf(g_om23p4[2][bt][h], g_om23p4[3][bt][h]));
            o += m23x;
        }
        outs_s[t][h] = o;
    }
    for (int h = tid; h < Hq; h += 512){
        float acc = 0.f;
        for (int d = 0; d < 32; ++d) acc += Wd[h * 32 + d] * ctx[d];
        wdc_s[h] = acc;
    }
    __syncthreads();
    int len = lens[b];
    if (tid < Tq){
        int t = tid;
        float acc = 0.f;
        for (int d = 0; d < 32; ++d) acc += bd[d] * ctx[d];
        for (int h = 0; h < Hq; ++h) acc += outs_s[t][h] * wdc_s[h];
        score_s[t] = (t < len) ? acc : -1e30f;
    }
    __syncthreads();
    if (tid == 0){
        float mx = -1e30f;
        for (int t = 0; t < Tq; ++t) mx = fmaxf(mx, score_s[t]);
        float sum = 0.f;
        for (int t = 0; t < Tq; ++t){ float e = expf(score_s[t] - mx); score_s[t] = e; sum += e; }
        float inv = 1.f / sum;
        for (int t = 0; t < Tq; ++t) score_s[t] *= inv;
    }
    __syncthreads();
    for (int h = tid; h < Hq; h += 512){
        float acc = 0.f;
        for (int t = 0; t < Tq; ++t) acc += score_s[t] * outs_s[t][h];
        pooled_s[h] = acc;
    }
    __syncthreads();
    for (int o = tid; o < OUTq; o += 512){
        float acc = bc[o];
        for (int h = 0; h < Hq; ++h) acc += pooled_s[h] * Wc[h * OUTq + o];
        out[b * OUTq + o] = sigm(acc);
    }
}

extern "C" void kernel_launch(void* const* d_in, const int* in_sizes, int n_in,
                              void* d_out, int out_size, void* d_ws, size_t ws_size,
                              hipStream_t stream){
    const float* code_x    = (const float*)d_in[0];
    const float* divided   = (const float*)d_in[1];
    const float* neighbors = (const float*)d_in[2];
    const int*   lens      = (const int*)  d_in[3];
    const float* adj       = (const float*)d_in[4];
    const float* c_emb     = (const float*)d_in[5];
    const float* n_emb     = (const float*)d_in[6];
    const float* u_emb     = (const float*)d_in[7];
    const float* Wg        = (const float*)d_in[8];
    const float* bg        = (const float*)d_in[9];
    const float* Wi        = (const float*)d_in[10];
    const float* bi        = (const float*)d_in[11];
    const float* Wh        = (const float*)d_in[12];
    const float* bh        = (const float*)d_in[13];
    const float* Wq_       = (const float*)d_in[14];
    const float* bq_       = (const float*)d_in[15];
    const float* Wk_       = (const float*)d_in[16];
    const float* bk_       = (const float*)d_in[17];
    const float* Wv_       = (const float*)d_in[18];
    const float* bv_       = (const float*)d_in[19];
    const float* Wd_       = (const float*)d_in[20];
    const float* bd_       = (const float*)d_in[21];
    const float* ctx       = (const float*)d_in[22];
    const float* Wc_       = (const float*)d_in[23];
    const float* bc_       = (const float*)d_in[24];
    float* out = (float*)d_out;

    hipLaunchKernelGGL(k_co,    dim3(4 * BTq), dim3(512), 0, stream, code_x, neighbors, adj,
                       Wg, bg, c_emb, n_emb);
    hipLaunchKernelGGL(k_mid,   dim3(4 * BTq), dim3(512), 0, stream, divided, u_emb,
                       Wk_, bk_, Wq_, bq_, Wv_, bv_, bg);
    hipLaunchKernelGGL(k_gru1,  dim3(4 * BTq), dim3(512), 0, stream, Wi, bi, Wh, bh);
    hipLaunchKernelGGL(k_gru1b, dim3(BTq),     dim3(512), 0, stream, Wi, bi, Wh, bh);
    hipLaunchKernelGGL(k_gru2f, dim3(Bq),      dim3(512), 0, stream, Wi, bi, Wh, bh,
                       lens, Wd_, bd_, ctx, Wc_, bc_, out);
}

// Round 16
// 257.105 us; speedup vs baseline: 1.0757x; 1.0757x over previous
//
#include <hip/hip_runtime.h>
#include <hip/hip_bf16.h>

#define Bq   8
#define Tq   16
#define Nq   1024
#define Cq   48
#define Gq   32
#define Hq   150
#define H3q  450
#define TAq  32
#define OUTq 1024
#define BTq  128

#define NC_CAP 128   // active code / neighbor rows per (b,t): Binom(1024,.06) mean 61 sd 7.6
#define NM_CAP 64    // m1 / m23 rows per (b,t): Binom(1024,.03) mean 30.7 sd 5.5
#define NACT   (2 * NC_CAP)
#define MTILE  16
#define NMH    (NM_CAP / 2)

__device__ __forceinline__ float lrelu(float x){ return x > 0.f ? x : 0.01f * x; }
__device__ __forceinline__ float sigm(float x){ return 1.f / (1.f + expf(-x)); }

// -------- device-global scratch (everything read is written earlier in the same call) --------
__device__ int   g_n1[BTq], g_n23[BTq], g_nchain[BTq], g_nchain2[BTq];
__device__ short g_list1[BTq][NM_CAP];
__device__ short g_list23[BTq][NM_CAP];        // row | (m2 ? 0x400 : 0), ascending row order
__device__ short g_mapc[BTq][Nq];              // row -> slot in c-list (-1 if inactive)
__device__ short g_mapn[BTq][Nq];              // row -> slot in nb-list (-1 if inactive)
__device__ int   g_chain[BTq][NM_CAP];         // (i_slot << 16) | prev_slot for m1->m1 rows
__device__ int   g_chain2[BTq][NM_CAP];        // deep-chain subset (source itself chain at t-1)
__device__ unsigned char g_cls[BTq][NM_CAP];   // per-m1-row class: 0 plain, 1 chain, 2 m23-sourced
__device__ float g_Pc[Nq][Gq];                 // c_emb @ Wg
__device__ float g_Pn[Nq][Gq];                 // n_emb @ Wg
__device__ float g_co[BTq][NC_CAP][Gq];        // co at active c rows (slot order)
__device__ float g_no[BTq][NC_CAP][Gq];        // no at active nb rows (slot order)
__device__ float g_hm23[BTq][NM_CAP][Hq];      // tanh(P@v) — ONLY rows m1 at t+1 are written/read
__device__ float g_om23p2[2][BTq][Hq];         // om23 partial max per query-parity half
__device__ float g_hm1[BTq][NM_CAP][Hq];       // GRU outputs at m1 rows (slot = list1 index)
__device__ float g_om1p2[2][BTq][Hq];          // om1 partial max over NON-chain m1 rows, per half
__device__ float g_om1c[BTq][Hq];              // om1 max over depth-1 chain rows (k_gru1b)

// inline gi helper (used ONLY for rare chain rows, ~1/block): gi = bi + co @ Wi at column h
__device__ __forceinline__ void gi3(const float* co_row, const float* Wi, const float* bi, int h,
                                    float& gr, float& gz, float& gn){
    gr = bi[h]; gz = bi[Hq + h]; gn = bi[2 * Hq + h];
    #pragma unroll
    for (int g = 0; g < Gq; ++g){
        float c = co_row[g];
        const float* w = Wi + g * H3q + h;
        gr += c * w[0];
        gz += c * w[Hq];
        gn += c * w[2 * Hq];
    }
}

// -------- K_pre: project embeddings through Wg once (linear: (adj@ce)@Wg = adj@(ce@Wg)) --------
__global__ __launch_bounds__(256) void k_pre(const float* c_emb, const float* n_emb, const float* Wg){
    int idx   = blockIdx.x * 256 + threadIdx.x;   // 65536 threads exactly
    int which = idx >> 15;
    int r     = (idx >> 5) & 1023;
    int g     = idx & 31;
    const float* emb = which ? n_emb : c_emb;
    float acc = 0.f;
    for (int c = 0; c < Cq; ++c)
        acc += emb[r * Cq + c] * Wg[c * Gq + g];
    if (which) g_Pn[r][g] = acc; else g_Pc[r][g] = acc;
}

// -------- K_co: sparse co/no as tiled gathered-GEMM. 2 blocks per (b,t) (odd/even m rows).
// R16: activity flags staged to LDS first; ballot runs over LDS (no serial global chain). --------
__global__ __launch_bounds__(512) void k_co(const float* code_x, const float* neighbors,
                                            const float* adj, const float* bg){
    int bt = blockIdx.x >> 1, half = blockIdx.x & 1, tid = threadIdx.x;
    __shared__ unsigned char cf_s[Nq], nf_s[Nq];   // 2 KB staged activity flags
    __shared__ short lc_s[NC_CAP], ln_s[NC_CAP];
    __shared__ short act_s[NACT];
    __shared__ int nc_s, nn_s;
    __shared__ float Pact_s[NACT][Gq];           // 32 KB
    __shared__ float A_s[MTILE][NACT];           // 16 KB
    __shared__ short mrow_s[MTILE];
    int wave = tid >> 6, lane = tid & 63;

    // coalesced flag staging (removes 16-iter serial global-latency ballot chain)
    for (int n = tid; n < Nq; n += 512){
        cf_s[n] = (code_x[bt * Nq + n]    > 0.f) ? 1 : 0;
        nf_s[n] = (neighbors[bt * Nq + n] > 0.f) ? 1 : 0;
    }
    __syncthreads();
    if (wave == 0){           // compact c-active rows (ballot over LDS flags)
        int base = 0;
        for (int start = 0; start < Nq; start += 64){
            int n = start + lane;
            int pred = cf_s[n];
            unsigned long long mm = __ballot(pred != 0);
            int pos = base + (int)__popcll(mm & ((1ull << lane) - 1ull));
            if (pred && pos < NC_CAP) lc_s[pos] = (short)n;
            base += (int)__popcll(mm);
        }
        if (lane == 0) nc_s = min(base, NC_CAP);
    } else if (wave == 1){    // compact nb-active rows
        int base = 0;
        for (int start = 0; start < Nq; start += 64){
            int n = start + lane;
            int pred = nf_s[n];
            unsigned long long mm = __ballot(pred != 0);
            int pos = base + (int)__popcll(mm & ((1ull << lane) - 1ull));
            if (pred && pos < NC_CAP) ln_s[pos] = (short)n;
            base += (int)__popcll(mm);
        }
        if (lane == 0) nn_s = min(base, NC_CAP);
    } else {                  // clear map half (384 threads, 1024 entries)
        if (half == 0) for (int n = tid - 128; n < Nq; n += 384) g_mapc[bt][n] = -1;
        else           for (int n = tid - 128; n < Nq; n += 384) g_mapn[bt][n] = -1;
    }
    __syncthreads();
    int nc = nc_s, nn = nn_s, total = nc + nn;

    for (int i = tid; i < total; i += 512) act_s[i] = (i < nc) ? lc_s[i] : ln_s[i - nc];
    if (half == 0) for (int i = tid; i < nc; i += 512) g_mapc[bt][lc_s[i]] = (short)i;
    else           for (int i = tid; i < nn; i += 512) g_mapn[bt][ln_s[i]] = (short)i;
    __syncthreads();

    for (int idx = tid; idx < total * Gq; idx += 512){
        int i = idx >> 5, g = idx & 31;
        Pact_s[i][g] = (i < nc) ? g_Pc[act_s[i]][g] : g_Pn[act_s[i]][g];
    }
    __syncthreads();

    int g = tid & 31, grp = tid >> 5;
    float bgv = bg[g];
    for (int rbase = half; rbase < total; rbase += 2 * MTILE){
        if (tid < MTILE){
            int r = rbase + 2 * tid;
            mrow_s[tid] = (r < total) ? act_s[r] : 0;
        }
        __syncthreads();
        int ntile = min(MTILE, (total - rbase + 1) / 2);
        for (int idx = tid; idx < ntile * total; idx += 512){
            int ti = idx / total, j = idx % total;
            A_s[ti][j] = adj[(size_t)mrow_s[ti] * Nq + act_s[j]];
        }
        __syncthreads();
        if (grp < ntile){
            int r = rbase + 2 * grp;
            float agg = 0.f;
            #pragma unroll 4
            for (int j = 0; j < total; ++j) agg += A_s[grp][j] * Pact_s[j][g];
            float v = lrelu(Pact_s[r][g] + agg + bgv);
            if (r < nc) g_co[bt][r][g]      = v;
            else        g_no[bt][r - nc][g] = v;
        }
        __syncthreads();
    }
}

// -------- K_mid (2 blocks per (b,t), odd/even query rows): lists + attention in LDS --------
__global__ __launch_bounds__(512) void k_mid(const float* divided, const float* u_emb,
                                             const float* Wk, const float* bk,
                                             const float* Wq_, const float* bq_,
                                             const float* Wv_, const float* bv_,
                                             const float* bg){
    int bt = blockIdx.x >> 1, half = blockIdx.x & 1, tid = threadIdx.x;
    int t = bt % Tq, btp = bt - 1;
    __shared__ unsigned char f1_s[Nq], f2_s[Nq], f3_s[Nq];   // 3 KB staged divided flags
    __shared__ short l1_s[NM_CAP], l23_s[NM_CAP];
    __shared__ unsigned char wm_s[NMH];
    __shared__ int n1_s, n23_s;
    __shared__ float co23_s[NM_CAP][Gq];         // 8 KB (all keys)
    __shared__ float qr_s[NM_CAP][Gq];           // 8 KB (all rows; v needs all)
    __shared__ float q_s[NMH][TAq + 1];          // my queries
    __shared__ float k_s[NM_CAP][TAq + 1];       // all keys
    __shared__ float s_s[NMH][NM_CAP + 1];       // my scores
    __shared__ float vv_s[NM_CAP][Hq];           // 38.4 KB (all values)
    __shared__ float hm_s[NMH][Hq];              // 19.2 KB (my outputs)
    int wave = tid >> 6, lane = tid & 63;

    // stage divided flags coalesced (removes serial global-latency ballot chain)
    for (int idx = tid; idx < Nq * 3; idx += 512){
        float v = divided[(size_t)bt * Nq * 3 + idx];
        int n = idx / 3, c = idx - n * 3;
        unsigned char f = (v > 0.f) ? 1 : 0;
        if (c == 0) f1_s[n] = f;
        else if (c == 1) f2_s[n] = f;
        else f3_s[n] = f;
    }
    __syncthreads();
    if (wave == 0){           // m1 list (ballot over LDS flags)
        int base = 0;
        for (int start = 0; start < Nq; start += 64){
            int n = start + lane;
            int pred = f1_s[n];
            unsigned long long mm = __ballot(pred != 0);
            int pos = base + (int)__popcll(mm & ((1ull << lane) - 1ull));
            if (pred && pos < NM_CAP) l1_s[pos] = (short)n;
            base += (int)__popcll(mm);
        }
        if (lane == 0) n1_s = min(base, NM_CAP);
    } else if (wave == 1){    // m23 list with m2 tag
        int base = 0;
        for (int start = 0; start < Nq; start += 64){
            int n = start + lane;
            int m2 = f2_s[n], m3 = f3_s[n];
            int pred = m2 | m3;
            unsigned long long mm = __ballot(pred != 0);
            int pos = base + (int)__popcll(mm & ((1ull << lane) - 1ull));
            if (pred && pos < NM_CAP) l23_s[pos] = (short)(n | (m2 ? 0x400 : 0));
            base += (int)__popcll(mm);
        }
        if (lane == 0) n23_s = min(base, NM_CAP);
    }
    __syncthreads();
    int n1 = n1_s, n23 = n23_s;
    if (half == 0){
        for (int i = tid; i < n1;  i += 512) g_list1[bt][i]  = l1_s[i];
        for (int i = tid; i < n23; i += 512) g_list23[bt][i] = l23_s[i];
        if (tid == 0){ g_n1[bt] = n1; g_n23[bt] = n23; }
    }
    if (t == 0 || n23 == 0) return;   // block-uniform; attention applies only at t>=1
    int nMy = (n23 > half) ? ((n23 - half + 1) >> 1) : 0;   // queries i with (i&1)==half

    // hm23 row is read downstream ONLY if its row is m1 at t+1 (k_gru1's m23-sourced GRU)
    for (int il = tid; il < nMy; il += 512){
        int row = l23_s[2 * il + half] & 1023;
        unsigned char wm = 0;
        if (t < Tq - 1) wm = (divided[((size_t)(bt + 1) * Nq + row) * 3] > 0.f) ? 1 : 0;
        wm_s[il] = wm;
    }
    for (int idx = tid; idx < n23 * Gq; idx += 512){
        int i = idx >> 5, g = idx & 31;
        co23_s[i][g] = g_co[bt][g_mapc[bt][l23_s[i] & 1023]][g];
    }
    for (int idx = tid; idx < n23 * Gq; idx += 512){
        int i = idx >> 5, g = idx & 31;
        int e = l23_s[i], row = e & 1023;
        float qv;
        if (e & 0x400){
            int slot = g_mapn[btp][row];
            qv = (slot >= 0) ? g_no[btp][slot][g] : lrelu(bg[g]);
        } else {
            qv = u_emb[row * Gq + g];
        }
        qr_s[i][g] = qv;
    }
    __syncthreads();
    // k for ALL keys; q for MY queries; v for ALL rows
    for (int idx = tid; idx < n23 * TAq; idx += 512){
        int i = idx >> 5, a = idx & 31;
        float acck = bk[a];
        #pragma unroll
        for (int g = 0; g < Gq; ++g) acck += co23_s[i][g] * Wk[g * TAq + a];
        k_s[i][a] = acck;
    }
    for (int idx = tid; idx < nMy * TAq; idx += 512){
        int il = idx >> 5, a = idx & 31;
        int i = 2 * il + half;
        float accq = bq_[a];
        #pragma unroll
        for (int g = 0; g < Gq; ++g) accq += qr_s[i][g] * Wq_[g * TAq + a];
        q_s[il][a] = accq;
    }
    for (int idx = tid; idx < n23 * Hq; idx += 512){
        int i = idx / Hq, h = idx % Hq;
        float acc = bv_[h];
        #pragma unroll
        for (int g = 0; g < Gq; ++g) acc += qr_s[i][g] * Wv_[g * Hq + h];
        vv_s[i][h] = acc;
    }
    __syncthreads();

    const float scale = 0.17677669529663687f;   // 1/sqrt(32)
    for (int idx = tid; idx < nMy * n23; idx += 512){
        int il = idx / n23, j = idx % n23;
        float acc = 0.f;
        #pragma unroll
        for (int a = 0; a < TAq; ++a) acc += q_s[il][a] * k_s[j][a];
        s_s[il][j] = acc * scale;
    }
    __syncthreads();
    for (int il = tid; il < nMy; il += 512){     // per-query softmax over the m23 key set
        float mx = -1e30f;
        for (int j = 0; j < n23; ++j) mx = fmaxf(mx, s_s[il][j]);
        float sum = 0.f;
        for (int j = 0; j < n23; ++j){ float e = expf(s_s[il][j] - mx); s_s[il][j] = e; sum += e; }
        float inv = 1.f / sum;
        for (int j = 0; j < n23; ++j) s_s[il][j] *= inv;
    }
    __syncthreads();
    for (int idx = tid; idx < nMy * Hq; idx += 512){
        int il = idx / Hq, h = idx % Hq;
        float acc = 0.f;
        for (int j = 0; j < n23; ++j) acc += s_s[il][j] * vv_s[j][h];
        hm_s[il][h] = tanhf(acc);
    }
    __syncthreads();
    for (int idx = tid; idx < nMy * Hq; idx += 512){   // spill only rows k_gru1 will read
        int il = idx / Hq, h = idx % Hq;
        if (wm_s[il]) g_hm23[bt][2 * il + half][h] = hm_s[il][h];
    }
    for (int h = tid; h < Hq; h += 512){
        float mx = -1e30f;
        for (int il = 0; il < nMy; ++il) mx = fmaxf(mx, hm_s[il][h]);
        g_om23p2[half][bt][h] = mx;
    }
}

// -------- K_gru1 (2 blocks per (b,t), odd/even m1 rows): coop gi in LDS, GRU in place --------
__global__ __launch_bounds__(512) void k_gru1(const float* Wi, const float* bi,
                                              const float* Wh, const float* bh){
    int bt = blockIdx.x >> 1, half = blockIdx.x & 1, tid = threadIdx.x;
    int t = bt % Tq, btp = bt - 1;
    __shared__ short map1p[Nq], map23p[Nq];      // 4 KB
    __shared__ short l1_s[NM_CAP];
    __shared__ unsigned char cls_s[NM_CAP];      // 0=plain, 1=chain, 2=m23-sourced (all rows)
    __shared__ int m23l_s[NM_CAP];               // my half's (i<<16)|prev_slot
    __shared__ int nf23_s;
    __shared__ float co1_s[NMH][Gq];             // 4 KB (my rows, local index il = i>>1)
    __shared__ float hb_s[Hq];
    __shared__ float ghf_s[H3q];
    __shared__ float gi_s[NMH][H3q];             // 57.6 KB; cols [0,Hq) overwritten with hm1
    int n1 = g_n1[bt];
    int nMy = (n1 > half) ? ((n1 - half + 1) >> 1) : 0;   // rows i with (i&1)==half
    for (int n = tid; n < Nq; n += 512){ map1p[n] = -1; map23p[n] = -1; }
    for (int i = tid; i < n1; i += 512) l1_s[i] = g_list1[bt][i];
    __syncthreads();
    if (t >= 1){
        int n1p = g_n1[btp];
        for (int i = tid; i < n1p; i += 512) map1p[g_list1[btp][i]] = (short)i;
        if (t >= 2){
            int n23p = g_n23[btp];
            for (int i = tid; i < n23p; i += 512) map23p[g_list23[btp][i] & 1023] = (short)i;
        }
    }
    __syncthreads();
    if (tid < 64){                                // single wave: classify + ballot-compact
        int i = tid;
        int cls = 0, sp = -1;
        if (i < n1 && t >= 1){
            int row = l1_s[i];
            if (map1p[row] >= 0){ cls = 1; sp = map1p[row]; }
            else if (t >= 2 && map23p[row] >= 0){ cls = 2; sp = map23p[row]; }
        }
        if (i < n1) cls_s[i] = (unsigned char)cls;
        if (half == 0 && i < n1) g_cls[bt][i] = (unsigned char)cls;
        unsigned long long mch = __ballot(cls == 1);
        unsigned long long m23 = __ballot(cls == 2 && (i & 1) == half);
        int pch = (int)__popcll(mch & ((1ull << i) - 1ull));
        int p23 = (int)__popcll(m23 & ((1ull << i) - 1ull));
        if (half == 0 && cls == 1) g_chain[bt][pch] = (i << 16) | sp;
        if (cls == 2 && (i & 1) == half) m23l_s[p23] = (i << 16) | sp;
        if (i == 0){
            nf23_s = (int)__popcll(m23);
            if (half == 0) g_nchain[bt] = (int)__popcll(mch);
        }
    }
    // stage co rows for MY m1 rows
    for (int idx = tid; idx < nMy * Gq; idx += 512){
        int il = idx >> 5, g = idx & 31;
        co1_s[il][g] = g_co[bt][g_mapc[bt][l1_s[2 * il + half]]][g];
    }
    __syncthreads();

    // cooperative gi: thread j < 450 holds Wi column in regs (Wi read once per block, coalesced)
    if (tid < H3q){
        float wcol[Gq];
        #pragma unroll
        for (int g = 0; g < Gq; ++g) wcol[g] = Wi[g * H3q + tid];
        float bij = bi[tid];
        for (int il = 0; il < nMy; ++il){
            float acc = bij;
            #pragma unroll
            for (int g = 0; g < Gq; ++g) acc += co1_s[il][g] * wcol[g];
            gi_s[il][tid] = acc;
        }
    }
    __syncthreads();

    // plain rows (mine): hp = 0, gh = bias only. Thread (il,h) sole reader+writer of gi_s[il][h]
    for (int idx = tid; idx < nMy * Hq; idx += 512){
        int il = idx / Hq, h = idx % Hq;
        int i = 2 * il + half;
        if (cls_s[i] != 0) continue;
        float gr = gi_s[il][h], gz = gi_s[il][Hq + h], gn = gi_s[il][2 * Hq + h];
        float r  = sigm(gr + bh[h]);
        float z  = sigm(gz + bh[Hq + h]);
        float ng = tanhf(gn + r * bh[2 * Hq + h]);
        gi_s[il][h] = (1.f - z) * ng;
    }
    __syncthreads();

    // m23-sourced rows in my half (~0.5 per block): full Wh matvec + GRU
    int nf23 = nf23_s;
    for (int f = 0; f < nf23; ++f){
        int pk = m23l_s[f]; int i = pk >> 16, sp = pk & 0xffff;
        int il = i >> 1;
        for (int h = tid; h < Hq; h += 512) hb_s[h] = g_hm23[btp][sp][h];
        __syncthreads();
        for (int j = tid; j < H3q; j += 512){
            float acc = bh[j];
            for (int k2 = 0; k2 < Hq; ++k2) acc += hb_s[k2] * Wh[k2 * H3q + j];
            ghf_s[j] = acc;
        }
        __syncthreads();
        for (int h = tid; h < Hq; h += 512){
            float gr = gi_s[il][h], gz = gi_s[il][Hq + h], gn = gi_s[il][2 * Hq + h];
            float r  = sigm(gr + ghf_s[h]);
            float z  = sigm(gz + ghf_s[Hq + h]);
            float ng = tanhf(gn + r * ghf_s[2 * Hq + h]);
            gi_s[il][h] = (1.f - z) * ng + z * hb_s[h];
        }
        __syncthreads();
    }

    // write my non-chain hm1 + my om1 partial max (chain rows: k_gru1b / k_gru2f)
    for (int idx = tid; idx < nMy * Hq; idx += 512){
        int il = idx / Hq, h = idx % Hq;
        int i = 2 * il + half;
        if (cls_s[i] != 1) g_hm1[bt][i][h] = gi_s[il][h];
    }
    for (int h = tid; h < Hq; h += 512){
        float mx = -1e30f;
        for (int il = 0; il < nMy; ++il)
            if (cls_s[2 * il + half] != 1) mx = fmaxf(mx, gi_s[il][h]);
        g_om1p2[half][bt][h] = mx;
    }
}

// -------- K_gru1b (parallel): depth-1 chain rows; defers deep-chain rows into g_chain2 --------
__global__ __launch_bounds__(512) void k_gru1b(const float* Wi, const float* bi,
                                               const float* Wh, const float* bh){
    int bt = blockIdx.x, tid = threadIdx.x;
    int t = bt % Tq, btp = bt - 1;
    __shared__ unsigned char defer_s[NM_CAP];
    __shared__ float co_s[Gq];
    __shared__ float hb_s[Hq];
    __shared__ float ghf_s[H3q];
    __shared__ float cmax_s[Hq];
    int nch = (t > 0) ? g_nchain[bt] : 0;
    for (int h = tid; h < Hq; h += 512) cmax_s[h] = -1e30f;
    if (tid < 64){
        int c = tid;
        int defer = 0;
        if (c < nch){
            int sp = g_chain[bt][c] & 0xffff;
            defer = (g_cls[btp][sp] == 1) ? 1 : 0;   // source is chain at t-1 -> defer
            defer_s[c] = (unsigned char)defer;
        }
        unsigned long long md = __ballot((c < nch) && defer);
        int pos = (int)__popcll(md & ((1ull << c) - 1ull));
        if ((c < nch) && defer) g_chain2[bt][pos] = g_chain[bt][c];
        if (c == 0) g_nchain2[bt] = (int)__popcll(md);
    }
    __syncthreads();
    for (int c = 0; c < nch; ++c){
        if (defer_s[c]) continue;                    // block-uniform
        int pk = g_chain[bt][c]; int i = pk >> 16, sp = pk & 0xffff;
        if (tid < Gq) co_s[tid] = g_co[bt][g_mapc[bt][g_list1[bt][i]]][tid];
        for (int h = tid; h < Hq; h += 512) hb_s[h] = g_hm1[btp][sp][h];
        __syncthreads();
        for (int j = tid; j < H3q; j += 512){
            float acc = bh[j];
            for (int k2 = 0; k2 < Hq; ++k2) acc += hb_s[k2] * Wh[k2 * H3q + j];
            ghf_s[j] = acc;
        }
        __syncthreads();
        for (int h = tid; h < Hq; h += 512){
            float gr, gz, gn;
            gi3(co_s, Wi, bi, h, gr, gz, gn);
            float r  = sigm(gr + ghf_s[h]);
            float z  = sigm(gz + ghf_s[Hq + h]);
            float ng = tanhf(gn + r * ghf_s[2 * Hq + h]);
            float v  = (1.f - z) * ng + z * hb_s[h];
            g_hm1[bt][i][h] = v;
            cmax_s[h] = fmaxf(cmax_s[h], v);
        }
        __syncthreads();
    }
    for (int h = tid; h < Hq; h += 512) g_om1c[bt][h] = cmax_s[h];
}

// -------- K_gru2f (8 blocks): serial deep-chain rows (~3 total), then outs + attention + classifier
__global__ __launch_bounds__(512) void k_gru2f(const float* Wi, const float* bi,
                                               const float* Wh, const float* bh,
                                               const int* lens, const float* Wd, const float* bd,
                                               const float* ctx, const float* Wc, const float* bc,
                                               float* out){
    int b = blockIdx.x, tid = threadIdx.x;
    __shared__ float co_s[Gq];
    __shared__ float hb_s[Hq];
    __shared__ float ghf_s[H3q];
    __shared__ float outs_s[Tq][Hq];
    __shared__ float wdc_s[Hq];
    __shared__ float score_s[Tq];
    __shared__ float pooled_s[Hq];
    for (int t = 1; t < Tq; ++t){
        int bt = b * Tq + t, btp = bt - 1;
        int nch2 = g_nchain2[bt];
        for (int c = 0; c < nch2; ++c){
            int pk = g_chain2[bt][c]; int i = pk >> 16, sp = pk & 0xffff;
            if (tid < Gq) co_s[tid] = g_co[bt][g_mapc[bt][g_list1[bt][i]]][tid];
            for (int h = tid; h < Hq; h += 512) hb_s[h] = g_hm1[btp][sp][h];
            __syncthreads();
            for (int j = tid; j < H3q; j += 512){
                float acc = bh[j];
                for (int k2 = 0; k2 < Hq; ++k2) acc += hb_s[k2] * Wh[k2 * H3q + j];
                ghf_s[j] = acc;
            }
            __syncthreads();
            for (int h = tid; h < Hq; h += 512){
                float gr, gz, gn;
                gi3(co_s, Wi, bi, h, gr, gz, gn);
                float r  = sigm(gr + ghf_s[h]);
                float z  = sigm(gz + ghf_s[Hq + h]);
                float ng = tanhf(gn + r * ghf_s[2 * Hq + h]);
                g_hm1[bt][i][h] = (1.f - z) * ng + z * hb_s[h];
            }
            __syncthreads();
        }
    }
    // ---- finalize outs + temporal attention + classifier ----
    for (int idx = tid; idx < Tq * Hq; idx += 512){
        int t = idx / Hq, h = idx % Hq;
        int bt = b * Tq + t;
        int n1 = g_n1[bt], n23 = (t > 0) ? g_n23[bt] : 0;
        float o = 0.f;
        if (n1 > 0){
            float mx = fmaxf(fmaxf(g_om1p2[0][bt][h], g_om1p2[1][bt][h]), g_om1c[bt][h]);
            int nd = (t > 0) ? g_nchain2[bt] : 0;
            for (int c = 0; c < nd; ++c){
                int i = g_chain2[bt][c] >> 16;
                mx = fmaxf(mx, g_hm1[bt][i][h]);
            }
            o = mx;
        }
        if (n23 > 0) o += fmaxf(g_om23p2[0][bt][h], g_om23p2[1][bt][h]);
        outs_s[t][h] = o;
    }
    for (int h = tid; h < Hq; h += 512){
        float acc = 0.f;
        for (int d = 0; d < 32; ++d) acc += Wd[h * 32 + d] * ctx[d];
        wdc_s[h] = acc;
    }
    __syncthreads();
    int len = lens[b];
    if (tid < Tq){
        int t = tid;
        float acc = 0.f;
        for (int d = 0; d < 32; ++d) acc += bd[d] * ctx[d];
        for (int h = 0; h < Hq; ++h) acc += outs_s[t][h] * wdc_s[h];
        score_s[t] = (t < len) ? acc : -1e30f;
    }
    __syncthreads();
    if (tid == 0){
        float mx = -1e30f;
        for (int t = 0; t < Tq; ++t) mx = fmaxf(mx, score_s[t]);
        float sum = 0.f;
        for (int t = 0; t < Tq; ++t){ float e = expf(score_s[t] - mx); score_s[t] = e; sum += e; }
        float inv = 1.f / sum;
        for (int t = 0; t < Tq; ++t) score_s[t] *= inv;
    }
    __syncthreads();
    for (int h = tid; h < Hq; h += 512){
        float acc = 0.f;
        for (int t = 0; t < Tq; ++t) acc += score_s[t] * outs_s[t][h];
        pooled_s[h] = acc;
    }
    __syncthreads();
    for (int o = tid; o < OUTq; o += 512){
        float acc = bc[o];
        for (int h = 0; h < Hq; ++h) acc += pooled_s[h] * Wc[h * OUTq + o];
        out[b * OUTq + o] = sigm(acc);
    }
}

extern "C" void kernel_launch(void* const* d_in, const int* in_sizes, int n_in,
                              void* d_out, int out_size, void* d_ws, size_t ws_size,
                              hipStream_t stream){
    const float* code_x    = (const float*)d_in[0];
    const float* divided   = (const float*)d_in[1];
    const float* neighbors = (const float*)d_in[2];
    const int*   lens      = (const int*)  d_in[3];
    const float* adj       = (const float*)d_in[4];
    const float* c_emb     = (const float*)d_in[5];
    const float* n_emb     = (const float*)d_in[6];
    const float* u_emb     = (const float*)d_in[7];
    const float* Wg        = (const float*)d_in[8];
    const float* bg        = (const float*)d_in[9];
    const float* Wi        = (const float*)d_in[10];
    const float* bi        = (const float*)d_in[11];
    const float* Wh        = (const float*)d_in[12];
    const float* bh        = (const float*)d_in[13];
    const float* Wq_       = (const float*)d_in[14];
    const float* bq_       = (const float*)d_in[15];
    const float* Wk_       = (const float*)d_in[16];
    const float* bk_       = (const float*)d_in[17];
    const float* Wv_       = (const float*)d_in[18];
    const float* bv_       = (const float*)d_in[19];
    const float* Wd_       = (const float*)d_in[20];
    const float* bd_       = (const float*)d_in[21];
    const float* ctx       = (const float*)d_in[22];
    const float* Wc_       = (const float*)d_in[23];
    const float* bc_       = (const float*)d_in[24];
    float* out = (float*)d_out;

    hipLaunchKernelGGL(k_pre,   dim3(256),     dim3(256), 0, stream, c_emb, n_emb, Wg);
    hipLaunchKernelGGL(k_co,    dim3(2 * BTq), dim3(512), 0, stream, code_x, neighbors, adj, bg);
    hipLaunchKernelGGL(k_mid,   dim3(2 * BTq), dim3(512), 0, stream, divided, u_emb,
                       Wk_, bk_, Wq_, bq_, Wv_, bv_, bg);
    hipLaunchKernelGGL(k_gru1,  dim3(2 * BTq), dim3(512), 0, stream, Wi, bi, Wh, bh);
    hipLaunchKernelGGL(k_gru1b, dim3(BTq),     dim3(512), 0, stream, Wi, bi, Wh, bh);
    hipLaunchKernelGGL(k_gru2f, dim3(Bq),      dim3(512), 0, stream, Wi, bi, Wh, bh,
                       lens, Wd_, bd_, ctx, Wc_, bc_, out);
}